// Round 3
// baseline (496.197 us; speedup 1.0000x reference)
//
#include <hip/hip_runtime.h>
#include <hip/hip_bf16.h>

// FP8LinearBase: y[M,N] = x[M,K] @ (w[N,K] * s[n/128,k/128])^T
// M=8192, K=4096, N=4096, fp32 in/out.
// pass1: fused convert x->bf16 and dequant w->bf16 into d_ws.
// pass2: bf16 GEMM, 256x256 tile, BK=64, MINIMUM-BARRIER schedule:
//   2 block-wide barriers per K-tile (B1 = operands-landed, B2 = B-region
//   consumed), counted vmcnt (never 0 mid-loop), 32-MFMA setprio clusters.
//   Rationale (round-2 post-mortem): 8-barrier lockstep serialized LDS-pipe
//   (512 cyc) + matrix-pipe (620 cyc) per phase; 2-barrier lets waves
//   free-run so the pipes overlap cross-wave (m114 mechanism).

#define MD 8192
#define ND 4096
#define KD 4096

typedef unsigned short u16;
typedef u16 u16x8 __attribute__((ext_vector_type(8)));
typedef short bf16x8 __attribute__((ext_vector_type(8)));   // 8 bf16 = 4 VGPR
typedef float f32x4 __attribute__((ext_vector_type(4)));

__device__ __forceinline__ u16 f2bf(float f) {
  union { float f; unsigned int u; } a; a.f = f;
  unsigned int u = a.u;
  u += 0x7fffu + ((u >> 16) & 1u);
  return (u16)(u >> 16);
}

__device__ __forceinline__ u16x8 pack8(float4 a, float4 b, float sc) {
  u16x8 r;
  r[0] = f2bf(a.x * sc); r[1] = f2bf(a.y * sc); r[2] = f2bf(a.z * sc); r[3] = f2bf(a.w * sc);
  r[4] = f2bf(b.x * sc); r[5] = f2bf(b.y * sc); r[6] = f2bf(b.z * sc); r[7] = f2bf(b.w * sc);
  return r;
}

// ---- pass 1: fused x->bf16 and w*scale->bf16 --------------------------------
__global__ __launch_bounds__(256) void k_cvt(const float4* __restrict__ x,
                                             const float4* __restrict__ w,
                                             const float* __restrict__ s,
                                             u16x8* __restrict__ xb,
                                             u16x8* __restrict__ wb) {
  const int XC = MD * (KD / 8);   // 4,194,304
  const int WC = ND * (KD / 8);   // 2,097,152
  int i = blockIdx.x * blockDim.x + threadIdx.x;
  int st = gridDim.x * blockDim.x;
  for (; i < XC + WC; i += st) {
    if (i < XC) {
      xb[i] = pack8(x[2 * i], x[2 * i + 1], 1.0f);
    } else {
      int c = i - XC;
      int k8 = c & 511;           // K/8 = 512 chunks per w-row
      int n  = c >> 9;
      float sc = s[(n >> 7) * (KD / 128) + (k8 >> 4)];
      wb[c] = pack8(w[2 * c], w[2 * c + 1], sc);
    }
  }
}

// ---- pass 2: bf16 GEMM, 256x256 tile, 2-barrier K-loop ----------------------
// LDS: lds[buf][region][128*64] bf16; regions 0=A0,1=A1 (buf = t&1, staged
// 1 tile ahead), 2=B0,3=B1 (staged 2 tiles ahead into the SAME buf index).
// 16B chunks stored at kb^(row&7): 0 bank conflicts (verified rounds 1-2).
// Hazard ledger:
//   B(t) reads (first half) vs B(t+2) stage (second half): separated by B2.
//   A(t+1) stage -> lds[bo][0,1]; last readers were tile t-1, drained pre-B1.
//   vmcnt(4) at tile end drains A(t+1)+B(t+1), leaves B(t+2) in flight.
__device__ __forceinline__ void stage_half(const u16* __restrict__ gbase,
                                           u16* lds_region, int tid) {
#pragma unroll
  for (int i = 0; i < 2; ++i) {
    int c   = i * 512 + tid;
    int row = c >> 3;
    int kb  = c & 7;
    int kbs = kb ^ (row & 7);     // inverse swizzle on the global source
    const u16* src = gbase + (long)row * KD + kbs * 8;
    __builtin_amdgcn_global_load_lds(
        (const __attribute__((address_space(1))) unsigned int*)src,
        (__attribute__((address_space(3))) unsigned int*)&lds_region[c * 8], 16, 0, 0);
  }
}

__device__ __forceinline__ bf16x8 ldfrag(const u16* reg, int rr, int kq) {
  return *(const bf16x8*)&reg[rr * 64 + ((kq ^ (rr & 7)) << 3)];
}

__global__ __launch_bounds__(512, 2) void k_gemm(const u16* __restrict__ A,
                                                 const u16* __restrict__ B,
                                                 float* __restrict__ C) {
  __shared__ u16 lds[2][4][128 * 64];   // 128 KiB -> 1 block/CU

  const int tid  = threadIdx.x;
  const int lane = tid & 63;
  const int wid  = tid >> 6;            // 0..7
  const int wr   = wid >> 2;            // 0..1  (M half -> A region)
  const int wc   = wid & 3;             // 0..3  (N quarter)
  const int l15  = lane & 15;
  const int l4h  = lane >> 4;           // 0..3

  // XCD-aware swizzle: 512 blocks, 64 contiguous per XCD, column-major tiles.
  const int nbid = (blockIdx.x & 7) * 64 + (blockIdx.x >> 3);
  const int bm   = nbid & 31;           // M tile 0..31
  const int bnt  = nbid >> 5;           // N tile 0..15
  const long brow = (long)bm * 256;
  const long bcol = (long)bnt * 256;

  const int regB = 2 + (wc >> 1);
  const int rB0  = (wc & 1) * 64;

  f32x4 acc[8][4] = {};
  bf16x8 a0[4], a1[4], bf0[4], bf1[4];

  const int NT = KD / 64;               // 64 K-tiles

  // ---- prologue: B(0), A(0), B(1) ----
  stage_half(B + bcol * KD, lds[0][2], tid);
  stage_half(B + (bcol + 128) * KD, lds[0][3], tid);
  stage_half(A + brow * KD, lds[0][0], tid);
  stage_half(A + (brow + 128) * KD, lds[0][1], tid);
  stage_half(B + bcol * KD + 64, lds[1][2], tid);
  stage_half(B + (bcol + 128) * KD + 64, lds[1][3], tid);
  asm volatile("s_waitcnt vmcnt(4)" ::: "memory");   // A(0)+B(0) landed
  asm volatile("s_barrier" ::: "memory");

  for (int t = 0; t < NT; ++t) {
    const int b  = t & 1;
    const int bo = b ^ 1;
    const u16* Ar = &lds[b][wr][0];
    const u16* Br = &lds[b][regB][0];

    // ================= first half: lo quadrants (mi 0-3), full K=64 ========
    // stage A(t+1) first so the loads fly under everything below
    if (t + 1 < NT) {
      stage_half(A + brow * KD + (long)(t + 1) * 64, lds[bo][0], tid);
      stage_half(A + (brow + 128) * KD + (long)(t + 1) * 64, lds[bo][1], tid);
    }
#pragma unroll
    for (int i = 0; i < 4; ++i) {
      a0[i]  = ldfrag(Ar, i * 16 + l15, l4h);
      a1[i]  = ldfrag(Ar, i * 16 + l15, 4 + l4h);
      bf0[i] = ldfrag(Br, rB0 + i * 16 + l15, l4h);
      bf1[i] = ldfrag(Br, rB0 + i * 16 + l15, 4 + l4h);
    }
    __builtin_amdgcn_s_setprio(1);
#pragma unroll
    for (int mi = 0; mi < 4; ++mi)
#pragma unroll
      for (int ni = 0; ni < 4; ++ni) {
        acc[mi][ni] = __builtin_amdgcn_mfma_f32_16x16x32_bf16(a0[mi], bf0[ni], acc[mi][ni], 0, 0, 0);
        acc[mi][ni] = __builtin_amdgcn_mfma_f32_16x16x32_bf16(a1[mi], bf1[ni], acc[mi][ni], 0, 0, 0);
      }
    __builtin_amdgcn_s_setprio(0);
    // B2: all waves' B(t) reads retired (drained before their MFMAs above)
    asm volatile("s_barrier" ::: "memory");

    // ================= second half: hi quadrants (mi 4-7) ==================
    if (t + 2 < NT) {
      stage_half(B + bcol * KD + (long)(t + 2) * 64, lds[b][2], tid);
      stage_half(B + (bcol + 128) * KD + (long)(t + 2) * 64, lds[b][3], tid);
    }
#pragma unroll
    for (int i = 0; i < 4; ++i) {
      a0[i] = ldfrag(Ar, 64 + i * 16 + l15, l4h);
      a1[i] = ldfrag(Ar, 64 + i * 16 + l15, 4 + l4h);
    }
    __builtin_amdgcn_s_setprio(1);
#pragma unroll
    for (int mi = 0; mi < 4; ++mi)
#pragma unroll
      for (int ni = 0; ni < 4; ++ni) {
        acc[4 + mi][ni] = __builtin_amdgcn_mfma_f32_16x16x32_bf16(a0[mi], bf0[ni], acc[4 + mi][ni], 0, 0, 0);
        acc[4 + mi][ni] = __builtin_amdgcn_mfma_f32_16x16x32_bf16(a1[mi], bf1[ni], acc[4 + mi][ni], 0, 0, 0);
      }
    __builtin_amdgcn_s_setprio(0);
    // B1 for tile t+1: A(t+1)+B(t+1) landed; B(t+2)'s 4 loads stay in flight
    if (t + 2 < NT) {
      asm volatile("s_waitcnt vmcnt(4)" ::: "memory");
    } else {
      asm volatile("s_waitcnt vmcnt(0)" ::: "memory");
    }
    asm volatile("s_barrier" ::: "memory");
  }

  // ---- epilogue: C/D layout col=lane&15, row=(lane>>4)*4+j (m89-verified) ----
  const int r0 = l4h * 4;
#pragma unroll
  for (int mi = 0; mi < 8; ++mi)
#pragma unroll
    for (int ni = 0; ni < 4; ++ni) {
      long row = brow + wr * 128 + mi * 16 + r0;
      long col = bcol + wc * 64 + ni * 16 + l15;
      float* p = C + row * ND + col;
#pragma unroll
      for (int j = 0; j < 4; ++j) p[(long)j * ND] = acc[mi][ni][j];
    }
}

// ---- insurance: correct fp32 path if workspace is too small -----------------
__global__ void k_fallback(const float* __restrict__ x, const float* __restrict__ w,
                           const float* __restrict__ s, float* __restrict__ out) {
  __shared__ float Ax[16][16];
  __shared__ float Bw[16][17];
  int tx = threadIdx.x, ty = threadIdx.y;
  long row = blockIdx.y * 16 + ty;
  long col = blockIdx.x * 16 + tx;
  float acc = 0.f;
  for (int kt = 0; kt < KD; kt += 16) {
    Ax[ty][tx] = x[row * KD + kt + tx];
    long wn = blockIdx.x * 16 + ty;
    Bw[ty][tx] = w[wn * KD + kt + tx] * s[(wn >> 7) * (KD / 128) + ((kt + tx) >> 7)];
    __syncthreads();
#pragma unroll
    for (int kk = 0; kk < 16; ++kk) acc += Ax[ty][kk] * Bw[tx][kk];
    __syncthreads();
  }
  out[row * ND + col] = acc;
}

extern "C" void kernel_launch(void* const* d_in, const int* in_sizes, int n_in,
                              void* d_out, int out_size, void* d_ws, size_t ws_size,
                              hipStream_t stream) {
  const float* x = (const float*)d_in[0];
  const float* w = (const float*)d_in[1];
  const float* s = (const float*)d_in[2];
  float* out = (float*)d_out;

  const size_t xb_bytes = (size_t)MD * KD * 2;
  const size_t wb_bytes = (size_t)ND * KD * 2;

  if (ws_size >= xb_bytes + wb_bytes) {
    u16* xb = (u16*)d_ws;
    u16* wb = (u16*)((char*)d_ws + xb_bytes);
    k_cvt<<<2048, 256, 0, stream>>>((const float4*)x, (const float4*)w, s,
                                    (u16x8*)xb, (u16x8*)wb);
    k_gemm<<<(MD / 256) * (ND / 256), 512, 0, stream>>>(xb, wb, out);
  } else {
    dim3 g(ND / 16, MD / 16), b(16, 16);
    k_fallback<<<g, b, 0, stream>>>(x, w, s, out);
  }
}

// Round 6
// 482.046 us; speedup vs baseline: 1.0294x; 1.0294x over previous
//
#include <hip/hip_runtime.h>
#include <hip/hip_bf16.h>

// FP8LinearBase: y[M,N] = x[M,K] @ (w[N,K] * s[n/128,k/128])^T
// M=8192, K=4096, N=4096, fp32 in/out.
// pass1: fused convert x->bf16 and dequant w->bf16 into d_ws.
// pass2: bf16 GEMM, 256x256 tile, BK=64, 2-barrier K-loop with IN-WAVE
//   SOFTWARE PIPELINING: 4 chunks of 16 MFMA; chunk c+1's ds_reads issue
//   before chunk c's MFMA cluster so the LDS pipe runs under the matrix pipe
//   (round-3 post-mortem: pipes were fully serialized by the read->lgkm->MFMA
//   convoy, 2260 LDS-cyc + 2483 MFMA-cyc adding to the measured 4609/tile).
// (Resubmission — rounds 4 and 5 both hit broker timeouts, never measured.)

#define MD 8192
#define ND 4096
#define KD 4096

typedef unsigned short u16;
typedef u16 u16x8 __attribute__((ext_vector_type(8)));
typedef short bf16x8 __attribute__((ext_vector_type(8)));   // 8 bf16 = 4 VGPR
typedef float f32x4 __attribute__((ext_vector_type(4)));

__device__ __forceinline__ u16 f2bf(float f) {
  union { float f; unsigned int u; } a; a.f = f;
  unsigned int u = a.u;
  u += 0x7fffu + ((u >> 16) & 1u);
  return (u16)(u >> 16);
}

__device__ __forceinline__ u16x8 pack8(float4 a, float4 b, float sc) {
  u16x8 r;
  r[0] = f2bf(a.x * sc); r[1] = f2bf(a.y * sc); r[2] = f2bf(a.z * sc); r[3] = f2bf(a.w * sc);
  r[4] = f2bf(b.x * sc); r[5] = f2bf(b.y * sc); r[6] = f2bf(b.z * sc); r[7] = f2bf(b.w * sc);
  return r;
}

// ---- pass 1: fused x->bf16 and w*scale->bf16 --------------------------------
__global__ __launch_bounds__(256) void k_cvt(const float4* __restrict__ x,
                                             const float4* __restrict__ w,
                                             const float* __restrict__ s,
                                             u16x8* __restrict__ xb,
                                             u16x8* __restrict__ wb) {
  const int XC = MD * (KD / 8);   // 4,194,304
  const int WC = ND * (KD / 8);   // 2,097,152
  int i = blockIdx.x * blockDim.x + threadIdx.x;
  int st = gridDim.x * blockDim.x;
  for (; i < XC + WC; i += st) {
    if (i < XC) {
      xb[i] = pack8(x[2 * i], x[2 * i + 1], 1.0f);
    } else {
      int c = i - XC;
      int k8 = c & 511;           // K/8 = 512 chunks per w-row
      int n  = c >> 9;
      float sc = s[(n >> 7) * (KD / 128) + (k8 >> 4)];
      wb[c] = pack8(w[2 * c], w[2 * c + 1], sc);
    }
  }
}

// ---- pass 2: bf16 GEMM, 256x256 tile, pipelined 2-barrier K-loop ------------
// LDS: lds[buf][region][128*64] bf16; regions 0=A0,1=A1 (buf=t&1, staged 1
// tile ahead into the other buffer), 2=B0,3=B1 (staged 2 tiles ahead, same
// buf index). 16B chunks stored at kb^(row&7): 0 bank conflicts (verified).
// Hazard ledger:
//   B(t) reads vs B(t+2) stage: lgkmcnt(0)+sched_barrier(0)+s_barrier (B2)
//     between them (rule #18: fence needed so MFMA+lgkm can't sink past).
//   A(t+1) stage -> lds[bo][0,1]: last readers (tile t-1) drained pre-B1.
//   vmcnt(4) at tile end drains A(t+1)+B(t+1), leaves B(t+2) in flight.
__device__ __forceinline__ void stage_half(const u16* __restrict__ gbase,
                                           u16* lds_region, int tid) {
#pragma unroll
  for (int i = 0; i < 2; ++i) {
    int c   = i * 512 + tid;
    int row = c >> 3;
    int kb  = c & 7;
    int kbs = kb ^ (row & 7);     // inverse swizzle on the global source
    const u16* src = gbase + (long)row * KD + kbs * 8;
    __builtin_amdgcn_global_load_lds(
        (const __attribute__((address_space(1))) unsigned int*)src,
        (__attribute__((address_space(3))) unsigned int*)&lds_region[c * 8], 16, 0, 0);
  }
}

__device__ __forceinline__ bf16x8 ldfrag(const u16* reg, int rr, int kq) {
  return *(const bf16x8*)&reg[rr * 64 + ((kq ^ (rr & 7)) << 3)];
}

__global__ __launch_bounds__(512, 2) void k_gemm(const u16* __restrict__ A,
                                                 const u16* __restrict__ B,
                                                 float* __restrict__ C) {
  __shared__ u16 lds[2][4][128 * 64];   // 128 KiB -> 1 block/CU

  const int tid  = threadIdx.x;
  const int lane = tid & 63;
  const int wid  = tid >> 6;            // 0..7
  const int wr   = wid >> 2;            // 0..1  (M half -> A region)
  const int wc   = wid & 3;             // 0..3  (N quarter)
  const int l15  = lane & 15;
  const int l4h  = lane >> 4;           // 0..3

  // XCD-aware swizzle: 512 blocks, 64 contiguous per XCD, column-major tiles.
  const int nbid = (blockIdx.x & 7) * 64 + (blockIdx.x >> 3);
  const int bm   = nbid & 31;           // M tile 0..31
  const int bnt  = nbid >> 5;           // N tile 0..15
  const long brow = (long)bm * 256;
  const long bcol = (long)bnt * 256;

  const int regB = 2 + (wc >> 1);
  const int rB0  = (wc & 1) * 64;

  f32x4 acc[8][4] = {};
  bf16x8 bf0[4], bf1[4];

  const int NT = KD / 64;               // 64 K-tiles

  // ---- prologue: B(0), A(0), B(1) ----
  stage_half(B + bcol * KD, lds[0][2], tid);
  stage_half(B + (bcol + 128) * KD, lds[0][3], tid);
  stage_half(A + brow * KD, lds[0][0], tid);
  stage_half(A + (brow + 128) * KD, lds[0][1], tid);
  stage_half(B + bcol * KD + 64, lds[1][2], tid);
  stage_half(B + (bcol + 128) * KD + 64, lds[1][3], tid);
  asm volatile("s_waitcnt vmcnt(4)" ::: "memory");   // A(0)+B(0) landed
  asm volatile("s_barrier" ::: "memory");

  for (int t = 0; t < NT; ++t) {
    const int b  = t & 1;
    const int bo = b ^ 1;
    const u16* Ar = &lds[b][wr][0];
    const u16* Br = &lds[b][regB][0];
    bf16x8 a0lo[4], a1lo[4], a0hi[4], a1hi[4];

    // ---- issue chunk0 + chunk1 fragment reads (16 ds_read_b128) ----
#pragma unroll
    for (int i = 0; i < 4; ++i) {
      a0lo[i] = ldfrag(Ar, i * 16 + l15, l4h);
      bf0[i]  = ldfrag(Br, rB0 + i * 16 + l15, l4h);
    }
#pragma unroll
    for (int i = 0; i < 4; ++i) {
      a1lo[i] = ldfrag(Ar, i * 16 + l15, 4 + l4h);
      bf1[i]  = ldfrag(Br, rB0 + i * 16 + l15, 4 + l4h);
    }
    // stage A(t+1): loads fly under the whole first half
    if (t + 1 < NT) {
      stage_half(A + brow * KD + (long)(t + 1) * 64, lds[bo][0], tid);
      stage_half(A + (brow + 128) * KD + (long)(t + 1) * 64, lds[bo][1], tid);
    }

    // ---- chunk0 MFMA: ks0 x lo (compiler waits lgkm for first 8 reads) ----
    __builtin_amdgcn_s_setprio(1);
#pragma unroll
    for (int mi = 0; mi < 4; ++mi)
#pragma unroll
      for (int ni = 0; ni < 4; ++ni)
        acc[mi][ni] = __builtin_amdgcn_mfma_f32_16x16x32_bf16(a0lo[mi], bf0[ni], acc[mi][ni], 0, 0, 0);
    __builtin_amdgcn_s_setprio(0);

    // ---- issue chunk2 reads (A hi, ks0) under chunk1's MFMAs ----
#pragma unroll
    for (int i = 0; i < 4; ++i) a0hi[i] = ldfrag(Ar, 64 + i * 16 + l15, l4h);

    // ---- chunk1 MFMA: ks1 x lo ----
    __builtin_amdgcn_s_setprio(1);
#pragma unroll
    for (int mi = 0; mi < 4; ++mi)
#pragma unroll
      for (int ni = 0; ni < 4; ++ni)
        acc[mi][ni] = __builtin_amdgcn_mfma_f32_16x16x32_bf16(a1lo[mi], bf1[ni], acc[mi][ni], 0, 0, 0);
    __builtin_amdgcn_s_setprio(0);

    // ---- B2: every wave's B(t) reads retired before B(t+2) restage ----
    asm volatile("s_waitcnt lgkmcnt(0)" ::: "memory");
    __builtin_amdgcn_sched_barrier(0);       // rule #18: pin MFMA/lgkm above
    asm volatile("s_barrier" ::: "memory");

    if (t + 2 < NT) {
      stage_half(B + bcol * KD + (long)(t + 2) * 64, lds[b][2], tid);
      stage_half(B + (bcol + 128) * KD + (long)(t + 2) * 64, lds[b][3], tid);
    }
    // ---- issue chunk3 reads (A hi, ks1) under chunk2's MFMAs ----
#pragma unroll
    for (int i = 0; i < 4; ++i) a1hi[i] = ldfrag(Ar, 64 + i * 16 + l15, 4 + l4h);

    // ---- chunk2 MFMA: ks0 x hi (reuses bf0) ----
    __builtin_amdgcn_s_setprio(1);
#pragma unroll
    for (int mi = 0; mi < 4; ++mi)
#pragma unroll
      for (int ni = 0; ni < 4; ++ni)
        acc[4 + mi][ni] = __builtin_amdgcn_mfma_f32_16x16x32_bf16(a0hi[mi], bf0[ni], acc[4 + mi][ni], 0, 0, 0);
    __builtin_amdgcn_s_setprio(0);

    // ---- chunk3 MFMA: ks1 x hi (reuses bf1) ----
    __builtin_amdgcn_s_setprio(1);
#pragma unroll
    for (int mi = 0; mi < 4; ++mi)
#pragma unroll
      for (int ni = 0; ni < 4; ++ni)
        acc[4 + mi][ni] = __builtin_amdgcn_mfma_f32_16x16x32_bf16(a1hi[mi], bf1[ni], acc[4 + mi][ni], 0, 0, 0);
    __builtin_amdgcn_s_setprio(0);

    // ---- B1 for tile t+1: A(t+1)+B(t+1) landed; B(t+2) stays in flight ----
    if (t + 2 < NT) {
      asm volatile("s_waitcnt vmcnt(4)" ::: "memory");
    } else {
      asm volatile("s_waitcnt vmcnt(0)" ::: "memory");
    }
    __builtin_amdgcn_sched_barrier(0);
    asm volatile("s_barrier" ::: "memory");
  }

  // ---- epilogue: C/D layout col=lane&15, row=(lane>>4)*4+j (m89-verified) ----
  const int r0 = l4h * 4;
#pragma unroll
  for (int mi = 0; mi < 8; ++mi)
#pragma unroll
    for (int ni = 0; ni < 4; ++ni) {
      long row = brow + wr * 128 + mi * 16 + r0;
      long col = bcol + wc * 64 + ni * 16 + l15;
      float* p = C + row * ND + col;
#pragma unroll
      for (int j = 0; j < 4; ++j) p[(long)j * ND] = acc[mi][ni][j];
    }
}

// ---- insurance: correct fp32 path if workspace is too small -----------------
__global__ void k_fallback(const float* __restrict__ x, const float* __restrict__ w,
                           const float* __restrict__ s, float* __restrict__ out) {
  __shared__ float Ax[16][16];
  __shared__ float Bw[16][17];
  int tx = threadIdx.x, ty = threadIdx.y;
  long row = blockIdx.y * 16 + ty;
  long col = blockIdx.x * 16 + tx;
  float acc = 0.f;
  for (int kt = 0; kt < KD; kt += 16) {
    Ax[ty][tx] = x[row * KD + kt + tx];
    long wn = blockIdx.x * 16 + ty;
    Bw[ty][tx] = w[wn * KD + kt + tx] * s[(wn >> 7) * (KD / 128) + ((kt + tx) >> 7)];
    __syncthreads();
#pragma unroll
    for (int kk = 0; kk < 16; ++kk) acc += Ax[ty][kk] * Bw[tx][kk];
    __syncthreads();
  }
  out[row * ND + col] = acc;
}

extern "C" void kernel_launch(void* const* d_in, const int* in_sizes, int n_in,
                              void* d_out, int out_size, void* d_ws, size_t ws_size,
                              hipStream_t stream) {
  const float* x = (const float*)d_in[0];
  const float* w = (const float*)d_in[1];
  const float* s = (const float*)d_in[2];
  float* out = (float*)d_out;

  const size_t xb_bytes = (size_t)MD * KD * 2;
  const size_t wb_bytes = (size_t)ND * KD * 2;

  if (ws_size >= xb_bytes + wb_bytes) {
    u16* xb = (u16*)d_ws;
    u16* wb = (u16*)((char*)d_ws + xb_bytes);
    k_cvt<<<2048, 256, 0, stream>>>((const float4*)x, (const float4*)w, s,
                                    (u16x8*)xb, (u16x8*)wb);
    k_gemm<<<(MD / 256) * (ND / 256), 512, 0, stream>>>(xb, wb, out);
  } else {
    dim3 g(ND / 16, MD / 16), b(16, 16);
    k_fallback<<<g, b, 0, stream>>>(x, w, s, out);
  }
}